// Round 4
// baseline (5673.793 us; speedup 1.0000x reference)
//
#include <hip/hip_runtime.h>
#include <cstdint>
#include <cstddef>

#define NN   4096      // neurons
#define NE   131072    // edges
#define NBAT 8         // batch
#define NT   128       // timesteps
#define NV   8192      // vocab
#define NK   4096      // = NN (GEMM K)
#define NM   1024      // = NBAT*NT (GEMM M)
#define DECAYF 0.99f
#define COOP_BLOCKS 256
#define COOP_THREADS 1024   // 8 batch x 8 strips x 16 nodes

typedef short bf16x8 __attribute__((ext_vector_type(8)));
typedef float f32x4 __attribute__((ext_vector_type(4)));
typedef unsigned short u16x8 __attribute__((ext_vector_type(8)));

__device__ __forceinline__ unsigned short f2bf(float f) {
  unsigned int u = __builtin_bit_cast(unsigned int, f);
  u = u + 0x7fffu + ((u >> 16) & 1u);   // round-to-nearest-even
  return (unsigned short)(u >> 16);
}

// Coherent (cross-XCD) access: served at the memory-side coherence point.
__device__ __forceinline__ float cload(const float* p) {
  return __hip_atomic_load(p, __ATOMIC_RELAXED, __HIP_MEMORY_SCOPE_AGENT);
}
__device__ __forceinline__ void cstore(float* p, float v) {
  __hip_atomic_store(p, v, __ATOMIC_RELAXED, __HIP_MEMORY_SCOPE_AGENT);
}
__device__ __forceinline__ int cloadi(const int* p) {
  return __hip_atomic_load(p, __ATOMIC_RELAXED, __HIP_MEMORY_SCOPE_AGENT);
}
__device__ __forceinline__ void cstorei(int* p, int v) {
  __hip_atomic_store(p, v, __ATOMIC_RELAXED, __HIP_MEMORY_SCOPE_AGENT);
}
__device__ __forceinline__ void cadd(float* p, float v) {
  (void)__hip_atomic_fetch_add(p, v, __ATOMIC_RELAXED, __HIP_MEMORY_SCOPE_AGENT);
}

// ---------------- prologue: CSR (by dst) + CSC (by src) build ----------------
__global__ void k_hist(const int* __restrict__ dst, const int* __restrict__ src,
                       int* __restrict__ cnt, int* __restrict__ cnt2) {
  int e = blockIdx.x * 256 + threadIdx.x;
  if (e < NE) {
    atomicAdd(&cnt[dst[e]], 1);
    atomicAdd(&cnt2[src[e]], 1);
  }
}

__global__ void k_scan(const int* __restrict__ cnt, int* __restrict__ row_ptr,
                       int* __restrict__ cursor) {
  __shared__ int lds[256];
  int tid = threadIdx.x;
  int base = tid * 16;
  int loc[16];
  int s = 0;
  #pragma unroll
  for (int i = 0; i < 16; ++i) { loc[i] = s; s += cnt[base + i]; }
  lds[tid] = s;
  __syncthreads();
  for (int off = 1; off < 256; off <<= 1) {
    int v = lds[tid];
    int a = (tid >= off) ? lds[tid - off] : 0;
    __syncthreads();
    lds[tid] = v + a;
    __syncthreads();
  }
  int myoff = (tid == 0) ? 0 : lds[tid - 1];
  #pragma unroll
  for (int i = 0; i < 16; ++i) {
    int rp = myoff + loc[i];
    row_ptr[base + i] = rp;
    cursor[base + i] = rp;
  }
  if (tid == 255) row_ptr[NN] = lds[255];
}

__global__ void k_build(const int* __restrict__ src, const int* __restrict__ dst,
                        const float* __restrict__ Gx, const float* __restrict__ Gy,
                        const float* __restrict__ Gs,
                        int* __restrict__ cursor, int* __restrict__ cursor2,
                        int* __restrict__ src_s, int* __restrict__ orig_s,
                        float* __restrict__ Gy_s, float* __restrict__ Gs_s,
                        int* __restrict__ csc_dst, float* __restrict__ csc_gx) {
  int e = blockIdx.x * 256 + threadIdx.x;
  if (e >= NE) return;
  int d = dst[e];
  int s = src[e];
  int pos = atomicAdd(&cursor[d], 1);
  src_s[pos] = s;
  orig_s[pos] = e;
  Gy_s[pos] = Gy[e];
  Gs_s[pos] = Gs[e];
  int pos2 = atomicAdd(&cursor2[s], 1);
  csc_dst[pos2] = d;
  csc_gx[pos2] = Gx[e];
}

// Gather all embeddings into (T, N, B) layout; also init y0 = X[:,0,:]
__global__ void k_gatherX(const int* __restrict__ idx, const float* __restrict__ Wemb,
                          float* __restrict__ Xbuf, float* __restrict__ ybuf) {
  __shared__ float tile[256 * 9];   // +1 pad stride to kill bank conflicts
  int t = blockIdx.x >> 4;
  int nc = (blockIdx.x & 15) << 8;
  int tid = threadIdx.x;
  #pragma unroll
  for (int bb = 0; bb < 8; ++bb) {
    int row = idx[bb * NT + t];     // idx is (B,T)
    tile[tid * 9 + bb] = Wemb[(size_t)row * NN + nc + tid];
  }
  __syncthreads();
  float* dp = Xbuf + (size_t)t * (NN * NBAT) + (size_t)nc * NBAT;
  #pragma unroll
  for (int kk = 0; kk < 8; ++kk) dp[tid * 8 + kk] = tile[tid * 9 + kk];
  if (t == 0) {
    float* yp = ybuf + (size_t)nc * NBAT;
    #pragma unroll
    for (int kk = 0; kk < 8; ++kk) yp[tid * 8 + kk] = tile[tid * 9 + kk];
  }
}

__global__ void k_convW(const float* __restrict__ W, unsigned short* __restrict__ Wbf) {
  size_t base = ((size_t)blockIdx.x * 256 + threadIdx.x) * 8;
  float4 a = *(const float4*)(W + base);
  float4 b = *(const float4*)(W + base + 4);
  u16x8 hv;
  hv[0] = f2bf(a.x); hv[1] = f2bf(a.y); hv[2] = f2bf(a.z); hv[3] = f2bf(a.w);
  hv[4] = f2bf(b.x); hv[5] = f2bf(b.y); hv[6] = f2bf(b.z); hv[7] = f2bf(b.w);
  *(u16x8*)(Wbf + base) = hv;
}

// ---------------- distributed grid barrier (1 cross-XCD hop) ----------------
// bar[blk] = monotone arrive generation. Every block's wave 0 polls all 256
// flags (4 coalesced loads/lane) and min-reduces via shfl butterfly.
// Data visibility: all cross-block state uses sc-coherent accesses drained
// by the pre-arrive __syncthreads (vmcnt 0), so flag>=target implies that
// block's data is at the coherence point.
__device__ __forceinline__ void gridbar(int* bar, int& gen) {
  __syncthreads();
  const int target = gen + 1;
  if (threadIdx.x < 64) {
    if (threadIdx.x == 0) cstorei(&bar[blockIdx.x], target);
    const int l = threadIdx.x;
    for (;;) {
      int v0 = cloadi(&bar[l]);
      int v1 = cloadi(&bar[l + 64]);
      int v2 = cloadi(&bar[l + 128]);
      int v3 = cloadi(&bar[l + 192]);
      int m = min(min(v0, v1), min(v2, v3));
      #pragma unroll
      for (int d = 1; d < 64; d <<= 1) m = min(m, __shfl_xor(m, d));
      if (m >= target) break;
      __builtin_amdgcn_s_sleep(1);
    }
  }
  gen = target;
  __syncthreads();
}

// ---------------- stage bodies ----------------
// S12: A[b,n] = sum_e sigma_e * x[b,src_e]; hebbian; sigma update.
// USE_ACC=false: x comes from Xbuf row (plain cached loads, already relu'd /
// exact embeddings). USE_ACC=true: x = relu(xacc[.]) via coherent loads.
template <bool USE_ACC>
__device__ __forceinline__ void s12_stage(
    int rs, int re, int h, int b, int nb8,
    const int* __restrict__ src_s, float* __restrict__ sigma_s,
    const float* __restrict__ Gs_s, const float* __restrict__ xp,
    const float* __restrict__ xacc, const float* __restrict__ ybuf,
    float* __restrict__ Abuf) {
  float xn = USE_ACC ? fmaxf(cload(&xacc[nb8]), 0.f) : xp[nb8];
  float acc = 0.f;
  for (int j = rs + h; j < re; j += 32) {
    int jj[4], sv[4];
    float sg[4], gs[4], xv[4], yv[4];
    bool act[4];
    #pragma unroll
    for (int u = 0; u < 4; ++u) {
      int jc = j + (u << 3);
      act[u] = jc < re;
      jj[u] = act[u] ? jc : j;     // clamped-safe index
    }
    #pragma unroll
    for (int u = 0; u < 4; ++u) sv[u] = src_s[jj[u]];
    #pragma unroll
    for (int u = 0; u < 4; ++u) {
      float sgu = sigma_s[jj[u]];
      float gsu = Gs_s[jj[u]];
      sg[u] = act[u] ? sgu : 0.f;
      gs[u] = act[u] ? gsu : 0.f;
    }
    #pragma unroll
    for (int u = 0; u < 4; ++u) {
      int sb = (sv[u] << 3) | b;
      xv[u] = USE_ACC ? fmaxf(cload(&xacc[sb]), 0.f) : xp[sb];
      yv[u] = cload(&ybuf[sb]);
    }
    #pragma unroll
    for (int u = 0; u < 4; ++u) {
      acc = fmaf(xv[u], sg[u], acc);        // OLD sigma (matches ref)
      float pv = yv[u] * xn;                // y_t[b,src]*x_t[b,dst]
      pv += __shfl_xor(pv, 1);
      pv += __shfl_xor(pv, 2);
      pv += __shfl_xor(pv, 4);              // sum over 8 batch lanes
      if (b == 0 && act[u])
        sigma_s[jj[u]] = (sg[u] + pv * 0.125f * gs[u]) * DECAYF;
    }
  }
  acc += __shfl_xor(acc, 8);
  acc += __shfl_xor(acc, 16);
  acc += __shfl_xor(acc, 32);               // combine 8 edge-strips
  if (h == 0) cstore(&Abuf[nb8], acc);
}

// S3 + fused S4-scatter: y[b,n] = sum relu(A[b,src])*Gy; then scatter
// y[b,n]*Gx_e into xacc[dst_e] over n's out-edges (CSC).
__device__ __forceinline__ void s3_scatter_stage(
    int rs, int re, int cs, int ce, int h, int b, int nb8,
    const int* __restrict__ src_s, const float* __restrict__ Gy_s,
    const float* __restrict__ Abuf, float* __restrict__ ybuf,
    const int* __restrict__ csc_dst, const float* __restrict__ csc_gx,
    float* __restrict__ xacc) {
  float acc = 0.f;
  for (int j = rs + h; j < re; j += 32) {
    int jj[4], sv[4];
    float gy[4], av[4];
    bool act[4];
    #pragma unroll
    for (int u = 0; u < 4; ++u) {
      int jc = j + (u << 3);
      act[u] = jc < re;
      jj[u] = act[u] ? jc : j;
    }
    #pragma unroll
    for (int u = 0; u < 4; ++u) sv[u] = src_s[jj[u]];
    #pragma unroll
    for (int u = 0; u < 4; ++u) {
      float gyu = Gy_s[jj[u]];
      gy[u] = act[u] ? gyu : 0.f;
    }
    #pragma unroll
    for (int u = 0; u < 4; ++u) av[u] = cload(&Abuf[(sv[u] << 3) | b]);
    #pragma unroll
    for (int u = 0; u < 4; ++u) acc = fmaf(fmaxf(av[u], 0.f), gy[u], acc);
  }
  acc += __shfl_xor(acc, 8);
  acc += __shfl_xor(acc, 16);
  acc += __shfl_xor(acc, 32);               // all lanes now hold y[n,b]
  if (h == 0) cstore(&ybuf[nb8], acc);
  // scatter over out-edges: lane (b,h) handles edges h, h+8, ...
  for (int jc = cs + h; jc < ce; jc += 8) {
    int d = csc_dst[jc];
    float gx = csc_gx[jc];
    cadd(&xacc[(d << 3) | b], acc * gx);
  }
}

// ---------------- persistent recurrence kernel ----------------
// 256 blocks x 1024 threads. g = b | h<<3 | n<<6: one wave per node
// (8 batch lanes x 8 edge strips), 16 nodes/block.
// Per timestep: P(S12-l0 + Abf/zero bookkeeping) |bar| Q(S3-l0+scatter x1)
// |bar| R(S12-l1, x=relu(xacc1)) |bar| S(S3-l1+scatter x2) |bar|
__global__ __launch_bounds__(COOP_THREADS, 4) void k_loop(
    const int* __restrict__ row_ptr, const int* __restrict__ src_s,
    const float* __restrict__ Gy_s, const float* __restrict__ Gs_s,
    float* __restrict__ sigma_s,
    const int* __restrict__ csc_ptr, const int* __restrict__ csc_dst,
    const float* __restrict__ csc_gx,
    const float* __restrict__ Xbuf, float* __restrict__ ybuf,
    float* __restrict__ xacc1, float* __restrict__ xacc2,
    float* __restrict__ Abuf, unsigned short* __restrict__ Abf, int* bar,
    const int* __restrict__ orig_s, float* __restrict__ sig_out) {
  const int tid = threadIdx.x;
  const int g = blockIdx.x * COOP_THREADS + tid;
  const int b = g & 7;
  const int h = (g >> 3) & 7;
  const int n = g >> 6;
  const int rs = row_ptr[n];
  const int re = row_ptr[n + 1];
  const int cs = csc_ptr[n];
  const int ce = csc_ptr[n + 1];
  const int nb8 = (n << 3) | b;
  int gen = 0;

  for (int t = 0; t < NT; ++t) {
    const float* xp = Xbuf + (size_t)t * (NN * NBAT);
    // ---- P: S12 layer0 (+ write Abf row t-1 from xacc2, zero xaccs) ----
    if (t > 0) {
      if (h == 0) {
        float v = cload(&xacc2[nb8]);
        Abf[(size_t)((b << 7) | (t - 1)) * NK + n] = f2bf(fmaxf(v, 0.f));
        cstore(&xacc2[nb8], 0.f);   // safe: same lane, after load consumed
      } else if (h == 1) {
        cstore(&xacc1[nb8], 0.f);   // xacc1 dead since R(t-1)
      }
    }
    s12_stage<false>(rs, re, h, b, nb8, src_s, sigma_s, Gs_s, xp, nullptr,
                     ybuf, Abuf);
    gridbar(bar, gen);
    // ---- Q: S3 layer0 + scatter into xacc1 ----
    s3_scatter_stage(rs, re, cs, ce, h, b, nb8, src_s, Gy_s, Abuf, ybuf,
                     csc_dst, csc_gx, xacc1);
    gridbar(bar, gen);
    // ---- R: S12 layer1, x = relu(xacc1) ----
    s12_stage<true>(rs, re, h, b, nb8, src_s, sigma_s, Gs_s, nullptr, xacc1,
                    ybuf, Abuf);
    gridbar(bar, gen);
    // ---- S: S3 layer1 + scatter into xacc2 ----
    s3_scatter_stage(rs, re, cs, ce, h, b, nb8, src_s, Gy_s, Abuf, ybuf,
                     csc_dst, csc_gx, xacc2);
    gridbar(bar, gen);
  }
  // epilogue (after final barrier): Abf row t=127, sigma un-permute
  if (h == 0) {
    float v = cload(&xacc2[nb8]);
    Abf[(size_t)((b << 7) | (NT - 1)) * NK + n] = f2bf(fmaxf(v, 0.f));
  }
  int jlo = row_ptr[blockIdx.x * 16];
  int jhi = row_ptr[blockIdx.x * 16 + 16];
  for (int j = jlo + tid; j < jhi; j += COOP_THREADS) sig_out[orig_s[j]] = sigma_s[j];
}

// ---------------- bf16 MFMA GEMM: C[m,v] = sum_k A[m,k]*Bw[v,k] + bias[v] ----------------
__global__ __launch_bounds__(256) void k_gemm(const unsigned short* __restrict__ A,
                                              const unsigned short* __restrict__ Bw,
                                              const float* __restrict__ bias,
                                              float* __restrict__ C) {
  __shared__ __align__(16) unsigned short As[128 * 32];
  __shared__ __align__(16) unsigned short Bs[128 * 32];
  const int m0 = blockIdx.y * 128;
  const int v0 = blockIdx.x * 128;
  const int wave = threadIdx.x >> 6;
  const int lane = threadIdx.x & 63;
  const int wm = wave >> 1;
  const int wv = wave & 1;
  f32x4 acc[4][4] = {};

  const int srow = lane >> 2;
  const int skc = (lane & 3) * 8;

  for (int k0 = 0; k0 < NK; k0 += 32) {
    #pragma unroll
    for (int c = 0; c < 2; ++c) {
      int chunk = wave * 2 + c;
      int row = chunk * 16 + srow;
      __builtin_amdgcn_global_load_lds(
          (const __attribute__((address_space(1))) void*)(A + (size_t)(m0 + row) * NK + k0 + skc),
          (__attribute__((address_space(3))) void*)(As + chunk * 512), 16, 0, 0);
      __builtin_amdgcn_global_load_lds(
          (const __attribute__((address_space(1))) void*)(Bw + (size_t)(v0 + row) * NK + k0 + skc),
          (__attribute__((address_space(3))) void*)(Bs + chunk * 512), 16, 0, 0);
    }
    __syncthreads();
    bf16x8 af[4], bq[4];
    #pragma unroll
    for (int mi = 0; mi < 4; ++mi)
      af[mi] = *(const bf16x8*)(As + ((wm * 64 + mi * 16 + (lane & 15)) * 32 + (lane >> 4) * 8));
    #pragma unroll
    for (int ni = 0; ni < 4; ++ni)
      bq[ni] = *(const bf16x8*)(Bs + ((wv * 64 + ni * 16 + (lane & 15)) * 32 + (lane >> 4) * 8));
    #pragma unroll
    for (int mi = 0; mi < 4; ++mi)
      #pragma unroll
      for (int ni = 0; ni < 4; ++ni)
        acc[mi][ni] = __builtin_amdgcn_mfma_f32_16x16x32_bf16(af[mi], bq[ni], acc[mi][ni], 0, 0, 0);
    __syncthreads();
  }

  #pragma unroll
  for (int mi = 0; mi < 4; ++mi) {
    int mrow = m0 + wm * 64 + mi * 16 + ((lane >> 4) << 2);
    #pragma unroll
    for (int ni = 0; ni < 4; ++ni) {
      int vcol = v0 + wv * 64 + ni * 16 + (lane & 15);
      float bs = bias[vcol];
      f32x4 a = acc[mi][ni];
      #pragma unroll
      for (int r = 0; r < 4; ++r) C[(size_t)(mrow + r) * NV + vcol] = a[r] + bs;
    }
  }
}

// ---------------- launch ----------------
extern "C" void kernel_launch(void* const* d_in, const int* in_sizes, int n_in,
                              void* d_out, int out_size, void* d_ws, size_t ws_size,
                              hipStream_t stream) {
  (void)in_sizes; (void)n_in; (void)out_size;
  const int*   idx  = (const int*)d_in[0];
  const int*   src  = (const int*)d_in[1];
  const int*   dst  = (const int*)d_in[2];
  const float* Wemb = (const float*)d_in[3];
  const float* Gx   = (const float*)d_in[4];
  const float* Gy   = (const float*)d_in[5];
  const float* Gs   = (const float*)d_in[6];
  const float* Wout = (const float*)d_in[7];
  const float* bout = (const float*)d_in[8];
  float* out = (float*)d_out;
  float* sig_out = out + (size_t)NM * NV;   // logits first, then sigma

  char* p = (char*)d_ws;
  // ---- zeroed prefix ----
  int*   bar     = (int*)p;                        // 4 KB (256 flags)
  int*   cnt     = (int*)(p + 4096);               // 16 KB
  int*   cnt2    = (int*)(p + 20480);              // 16 KB
  float* xacc1   = (float*)(p + 36864);            // 128 KB
  float* xacc2   = (float*)(p + 167936);           // 128 KB
  float* sigma_s = (float*)(p + 299008);           // 512 KB
  const size_t msz = 299008 + (size_t)NE * 4;      // 823296 B
  size_t off = msz;
  // ---- rest ----
  int*   row_ptr = (int*)(p + off); off += 16640;          // 4097 ints, padded
  int*   cursor  = (int*)(p + off); off += 16384;
  int*   csc_ptr = (int*)(p + off); off += 16640;
  int*   cursor2 = (int*)(p + off); off += 16384;
  int*   src_s   = (int*)(p + off); off += (size_t)NE * 4;
  int*   orig_s  = (int*)(p + off); off += (size_t)NE * 4;
  float* Gy_s    = (float*)(p + off); off += (size_t)NE * 4;
  float* Gs_s    = (float*)(p + off); off += (size_t)NE * 4;
  int*   csc_dst = (int*)(p + off); off += (size_t)NE * 4;
  float* csc_gx  = (float*)(p + off); off += (size_t)NE * 4;
  float* ybuf    = (float*)(p + off); off += (size_t)NN * NBAT * 4;
  float* Abuf    = (float*)(p + off); off += (size_t)NN * NBAT * 4;
  float* Xbuf    = (float*)(p + off); off += (size_t)NT * NN * NBAT * 4;   // 16 MB
  unsigned short* Abf = (unsigned short*)(p + off); off += (size_t)NM * NK * 2; // 8 MB
  unsigned short* Wbf = (unsigned short*)(p + off); off += (size_t)NV * NK * 2; // 64 MB
  if (ws_size < off) return;   // ~92 MiB required

  hipMemsetAsync(d_ws, 0, msz, stream);
  k_hist<<<NE / 256, 256, 0, stream>>>(dst, src, cnt, cnt2);
  k_scan<<<1, 256, 0, stream>>>(cnt, row_ptr, cursor);
  k_scan<<<1, 256, 0, stream>>>(cnt2, csc_ptr, cursor2);
  k_build<<<NE / 256, 256, 0, stream>>>(src, dst, Gx, Gy, Gs, cursor, cursor2,
                                        src_s, orig_s, Gy_s, Gs_s, csc_dst, csc_gx);
  k_gatherX<<<NT * 16, 256, 0, stream>>>(idx, Wemb, Xbuf, ybuf);
  k_convW<<<(NV * NK) / (256 * 8), 256, 0, stream>>>(Wout, Wbf);
  k_loop<<<COOP_BLOCKS, COOP_THREADS, 0, stream>>>(row_ptr, src_s, Gy_s, Gs_s,
      sigma_s, csc_ptr, csc_dst, csc_gx, Xbuf, ybuf, xacc1, xacc2, Abuf, Abf,
      bar, orig_s, sig_out);
  k_gemm<<<dim3(NV / 128, NM / 128), 256, 0, stream>>>(Abf, Wbf, bout, out);
}